// Round 1
// 1351.746 us; speedup vs baseline: 1.0518x; 1.0518x over previous
//
#include <hip/hip_runtime.h>
#include <hip/hip_bf16.h>

typedef __attribute__((ext_vector_type(8))) short short8;
typedef __attribute__((ext_vector_type(4))) float f32x4;
using bf16 = __hip_bfloat16;

#define DEV static __device__ __forceinline__

DEV float bf2f(bf16 v) { return __bfloat162float(v); }
DEV bf16 f2bf(float v) { return __float2bfloat16(v); }

DEV void gld_lds16(const void* g, void* l) {
  __builtin_amdgcn_global_load_lds(
      (const __attribute__((address_space(1))) void*)g,
      (__attribute__((address_space(3))) void*)l, 16, 0, 0);
}

// ---------------- weight convert+transpose: (K,N) f32 -> (N,K) bf16 ----------------
__global__ __launch_bounds__(256)
void wconv_kernel(const float* __restrict__ w, bf16* __restrict__ wT, int K, int N) {
  __shared__ float tile[32][33];
  const int kt = blockIdx.x * 32, nt = blockIdx.y * 32;
  const int tx = threadIdx.x & 31, ty = threadIdx.x >> 5;  // ty 0..7
#pragma unroll
  for (int i = 0; i < 32; i += 8)
    tile[ty + i][tx] = w[(size_t)(kt + ty + i) * N + nt + tx];
  __syncthreads();
#pragma unroll
  for (int i = 0; i < 32; i += 8)
    wT[(size_t)(nt + ty + i) * K + kt + tx] = f2bf(tile[tx][ty + i]);
}

// ---------------- LayerNorm (D=1024), f32 in -> bf16 out ----------------
__global__ __launch_bounds__(256)
void ln_kernel(const float* __restrict__ x, const float* __restrict__ g,
               const float* __restrict__ b, bf16* __restrict__ out) {
  const int row = blockIdx.x;
  const int t = threadIdx.x;
  const float4 v = ((const float4*)(x + (size_t)row * 1024))[t];
  float s = v.x + v.y + v.z + v.w;
  float ss = v.x * v.x + v.y * v.y + v.z * v.z + v.w * v.w;
#pragma unroll
  for (int off = 32; off > 0; off >>= 1) {
    s += __shfl_down(s, off);
    ss += __shfl_down(ss, off);
  }
  __shared__ float red[8];
  if ((t & 63) == 0) { red[(t >> 6) * 2] = s; red[(t >> 6) * 2 + 1] = ss; }
  __syncthreads();
  s = red[0] + red[2] + red[4] + red[6];
  ss = red[1] + red[3] + red[5] + red[7];
  const float mu = s * (1.f / 1024.f);
  const float rstd = rsqrtf(ss * (1.f / 1024.f) - mu * mu + 1e-5f);
  const float4 g4 = ((const float4*)g)[t];
  const float4 b4 = ((const float4*)b)[t];
  struct alignas(8) B4 { bf16 v[4]; } o;
  o.v[0] = f2bf((v.x - mu) * rstd * g4.x + b4.x);
  o.v[1] = f2bf((v.y - mu) * rstd * g4.y + b4.y);
  o.v[2] = f2bf((v.z - mu) * rstd * g4.z + b4.z);
  o.v[3] = f2bf((v.w - mu) * rstd * g4.w + b4.w);
  *(B4*)(out + (size_t)row * 1024 + t * 4) = o;
}

// ---------------- m97-style 128x128 bf16 MFMA GEMM, NT (A:MxK, BT:NxK) ----------------
// kept for mw3 chunks (grid would be 64 blocks at 256^2 tiles -> 25% of GPU)
template <int EPI>
__global__ __launch_bounds__(256, 2)
void gemm128(const bf16* __restrict__ A, const bf16* __restrict__ BT,
             const float* __restrict__ bias, const float* __restrict__ res,
             void* __restrict__ C, int M, int N, int K) {
  __shared__ short As[128 * 64];
  __shared__ short Bs[128 * 64];
  const int tid = threadIdx.x;
  const int l = tid & 63;
  const int w = tid >> 6;
  const int wr = w >> 1, wc = w & 1;

  const int nbn = N >> 7;
  const int nwg = gridDim.x;
  const int bid = blockIdx.x;
  const int q = nwg >> 3, r = nwg & 7;
  const int xcd = bid & 7, lin = bid >> 3;
  const int wg = (xcd < r ? xcd * (q + 1) : r * (q + 1) + (xcd - r) * q) + lin;
  const int bm = wg / nbn, bn = wg % nbn;

  const bf16* Ab = A + (size_t)bm * 128 * K;
  const bf16* Bb = BT + (size_t)bn * 128 * K;

  f32x4 acc[4][4];
#pragma unroll
  for (int i = 0; i < 4; ++i)
#pragma unroll
    for (int j = 0; j < 4; ++j) acc[i][j] = (f32x4){0.f, 0.f, 0.f, 0.f};

  const int srow = l >> 3;
  const int scol = (((l & 7) ^ (l >> 3)) << 3);

  for (int k0 = 0; k0 < K; k0 += 64) {
    __syncthreads();
#pragma unroll
    for (int p = 0; p < 4; ++p) {
      const int rowA = p * 32 + w * 8 + srow;
      gld_lds16(Ab + (size_t)rowA * K + k0 + scol, As + (p * 32 + w * 8) * 64);
      gld_lds16(Bb + (size_t)rowA * K + k0 + scol, Bs + (p * 32 + w * 8) * 64);
    }
    __syncthreads();
    const int xr = (l & 7) << 3;
#pragma unroll
    for (int kk = 0; kk < 2; ++kk) {
      short8 fa[4], fb[4];
#pragma unroll
      for (int m = 0; m < 4; ++m)
        fa[m] = *(const short8*)&As[(wr * 64 + m * 16 + (l & 15)) * 64 +
                                    ((kk * 32 + (l >> 4) * 8) ^ xr)];
#pragma unroll
      for (int n = 0; n < 4; ++n)
        fb[n] = *(const short8*)&Bs[(wc * 64 + n * 16 + (l & 15)) * 64 +
                                    ((kk * 32 + (l >> 4) * 8) ^ xr)];
#pragma unroll
      for (int m = 0; m < 4; ++m)
#pragma unroll
        for (int n = 0; n < 4; ++n)
          acc[m][n] = __builtin_amdgcn_mfma_f32_16x16x32_bf16(fa[m], fb[n], acc[m][n], 0, 0, 0);
    }
  }

  const int lc = l & 15;
  const int lr = (l >> 4) * 4;
#pragma unroll
  for (int n = 0; n < 4; ++n) {
    const int col = bn * 128 + wc * 64 + n * 16 + lc;
    const float bv = bias[col];
#pragma unroll
    for (int m = 0; m < 4; ++m) {
      const int row = bm * 128 + wr * 64 + m * 16 + lr;
#pragma unroll
      for (int r2 = 0; r2 < 4; ++r2) {
        float v = acc[m][n][r2] + bv;
        const size_t off = (size_t)(row + r2) * N + col;
        if constexpr (EPI == 1) v = v / (1.f + __expf(-v));
        if constexpr (EPI == 2) {
          ((float*)C)[off] = res[off] + v;
        } else {
          ((bf16*)C)[off] = f2bf(v);
        }
      }
    }
  }
  (void)M;
}

// ---------------- 256x256 8-phase bf16 MFMA GEMM (T2+T3+T4+T5), NT layout ----------------
// 512 threads = 8 waves (2M x 4N); per-wave 128x64 output (acc[8][4]).
// LDS: 2 bufs x (256x64 A + 256x64 B) bf16 = 128 KiB. BK=64, 2 K-tiles/iter, 8 phases.
// Stage: global_load_lds w/ linear LDS dest + pre-swizzled per-lane SOURCE col
// (col16 ^= row&7 involution); ds_read applies the same XOR -> bank-conflict-free.
// Counted vmcnt(4) only at K-tile boundaries (never 0 in steady loop).
// Stage ledger (iter i computes tiles 2i,2i+1; buf = tile&1):
//  p0: A-up(2i+1)->buf1   p1: A-lo(2i+1)->buf1   p2: B-up(2i+2)->buf0  p3: B-lo(2i+2)->buf0
//  p4: A-up(2i+2)->buf0   p5: A-lo(2i+2)->buf0   p6: B-up(2i+3)->buf1  p7: B-lo(2i+3)->buf1
// Every stage issue is >=1 barrier after the lgkmcnt(0)-completed last read of its region.
template <int EPI>
__global__ __launch_bounds__(512, 2)
void gemm256(const bf16* __restrict__ A, const bf16* __restrict__ BT,
             const float* __restrict__ bias, const float* __restrict__ res,
             void* __restrict__ C, int M, int N, int K) {
  __shared__ alignas(16) short As[2][256 * 64];
  __shared__ alignas(16) short Bs[2][256 * 64];
  const int tid = threadIdx.x;
  const int l = tid & 63;
  const int w = tid >> 6;   // 0..7
  const int wr = w >> 2;    // 0..1 (M half)
  const int wc = w & 3;     // 0..3 (N quarter)

  const int nbn = N >> 8;
  const int nwg = gridDim.x;
  const int bid = blockIdx.x;
  const int q = nwg >> 3, r = nwg & 7;
  const int xcd = bid & 7, lin = bid >> 3;
  const int wg = (xcd < r ? xcd * (q + 1) : r * (q + 1) + (xcd - r) * q) + lin;
  const int bm = wg / nbn, bn = wg % nbn;

  const bf16* Ab = A + (size_t)bm * 256 * K;
  const bf16* Bb = BT + (size_t)bn * 256 * K;

  const int gcol = ((l & 7) ^ (l >> 3)) << 3;  // pre-swizzled source col (shorts)
  const int fr = l & 15;
  const int kq = (l >> 4) << 3;
  const int xr = (l & 7) << 3;

  f32x4 acc[8][4];
#pragma unroll
  for (int i = 0; i < 8; ++i)
#pragma unroll
    for (int j = 0; j < 4; ++j) acc[i][j] = (f32x4){0.f, 0.f, 0.f, 0.f};

  short8 fa[2][2], fb[4][2];

#define STAGE_A(BUF, HALF, KT)                                                     \
  do {                                                                             \
    const int rl_ = (HALF) * 128 + w * 16;                                         \
    gld_lds16(Ab + (size_t)(rl_ + (l >> 3)) * K + (KT) * 64 + gcol,                \
              &As[BUF][rl_ * 64]);                                                 \
    gld_lds16(Ab + (size_t)(rl_ + 8 + (l >> 3)) * K + (KT) * 64 + gcol,            \
              &As[BUF][(rl_ + 8) * 64]);                                           \
  } while (0)

#define STAGE_B(BUF, HALF, KT)                                                     \
  do {                                                                             \
    const int rl_ = (HALF) * 128 + w * 16;                                         \
    gld_lds16(Bb + (size_t)(rl_ + (l >> 3)) * K + (KT) * 64 + gcol,                \
              &Bs[BUF][rl_ * 64]);                                                 \
    gld_lds16(Bb + (size_t)(rl_ + 8 + (l >> 3)) * K + (KT) * 64 + gcol,            \
              &Bs[BUF][(rl_ + 8) * 64]);                                           \
  } while (0)

#define LDA2(BUF, M0)                                                                          \
  do {                                                                                         \
    fa[0][0] = *(const short8*)&As[BUF][(wr * 128 + (M0) * 16 + fr) * 64 + (kq ^ xr)];         \
    fa[0][1] = *(const short8*)&As[BUF][(wr * 128 + (M0) * 16 + fr) * 64 + ((32 + kq) ^ xr)];  \
    fa[1][0] = *(const short8*)&As[BUF][(wr * 128 + (M0)*16 + 16 + fr) * 64 + (kq ^ xr)];      \
    fa[1][1] = *(const short8*)&As[BUF][(wr * 128 + (M0)*16 + 16 + fr) * 64 + ((32 + kq) ^ xr)]; \
  } while (0)

#define LDB8(BUF)                                                                              \
  do {                                                                                         \
    _Pragma("unroll") for (int n_ = 0; n_ < 4; ++n_) {                                         \
      fb[n_][0] = *(const short8*)&Bs[BUF][(wc * 64 + n_ * 16 + fr) * 64 + (kq ^ xr)];         \
      fb[n_][1] = *(const short8*)&Bs[BUF][(wc * 64 + n_ * 16 + fr) * 64 + ((32 + kq) ^ xr)];  \
    }                                                                                          \
  } while (0)

#define MMA_PAIR(M0)                                                                           \
  do {                                                                                         \
    _Pragma("unroll") for (int n_ = 0; n_ < 4; ++n_) {                                         \
      acc[M0][n_] = __builtin_amdgcn_mfma_f32_16x16x32_bf16(fa[0][0], fb[n_][0], acc[M0][n_], 0, 0, 0); \
      acc[(M0) + 1][n_] = __builtin_amdgcn_mfma_f32_16x16x32_bf16(fa[1][0], fb[n_][0], acc[(M0) + 1][n_], 0, 0, 0); \
      acc[M0][n_] = __builtin_amdgcn_mfma_f32_16x16x32_bf16(fa[0][1], fb[n_][1], acc[M0][n_], 0, 0, 0); \
      acc[(M0) + 1][n_] = __builtin_amdgcn_mfma_f32_16x16x32_bf16(fa[1][1], fb[n_][1], acc[(M0) + 1][n_], 0, 0, 0); \
    }                                                                                          \
  } while (0)

#define PHASE(CBUF, M0, ...)                                                       \
  do {                                                                             \
    LDA2(CBUF, M0);                                                                \
    __VA_ARGS__;                                                                   \
    __builtin_amdgcn_s_barrier();                                                  \
    asm volatile("s_waitcnt lgkmcnt(0)");                                          \
    __builtin_amdgcn_s_setprio(1);                                                 \
    MMA_PAIR(M0);                                                                  \
    __builtin_amdgcn_s_setprio(0);                                                 \
    __builtin_amdgcn_s_barrier();                                                  \
  } while (0)

#define PHASE_END(CBUF, ...)                                                       \
  do {                                                                             \
    LDA2(CBUF, 6);                                                                 \
    __VA_ARGS__;                                                                   \
    __builtin_amdgcn_s_barrier();                                                  \
    asm volatile("s_waitcnt lgkmcnt(0)");                                          \
    __builtin_amdgcn_s_setprio(1);                                                 \
    MMA_PAIR(6);                                                                   \
    __builtin_amdgcn_s_setprio(0);                                                 \
    if (more) asm volatile("s_waitcnt vmcnt(4)" ::: "memory");                     \
    else      asm volatile("s_waitcnt vmcnt(0)" ::: "memory");                     \
    __builtin_amdgcn_s_barrier();                                                  \
  } while (0)

  // prologue: tile0 (A+B) -> buf0, B(1) -> buf1 ; 12 loads, oldest 8 = tile0
  STAGE_A(0, 0, 0); STAGE_A(0, 1, 0);
  STAGE_B(0, 0, 0); STAGE_B(0, 1, 0);
  STAGE_B(1, 0, 1); STAGE_B(1, 1, 1);
  asm volatile("s_waitcnt vmcnt(4)" ::: "memory");
  __builtin_amdgcn_s_barrier();

  const int NT = K >> 6;   // 64-wide K-tiles (NT even, >= 4 for all our shapes)
  const int NI = NT >> 1;
#pragma unroll 1
  for (int i = 0; i < NI; ++i) {
    const int t0 = i * 2;
    const bool more = (i + 1) < NI;
    // ---- K-tile t0 (buf0): phases 0-3 ----
    LDB8(0);
    PHASE(0, 0, STAGE_A(1, 0, t0 + 1));
    PHASE(0, 2, STAGE_A(1, 1, t0 + 1));
    PHASE(0, 4, if (more) STAGE_B(0, 0, t0 + 2));
    PHASE_END(0, if (more) STAGE_B(0, 1, t0 + 2));
    // ---- K-tile t0+1 (buf1): phases 4-7 ----
    LDB8(1);
    PHASE(1, 0, if (more) STAGE_A(0, 0, t0 + 2));
    PHASE(1, 2, if (more) STAGE_A(0, 1, t0 + 2));
    PHASE(1, 4, if (more) STAGE_B(1, 0, t0 + 3));
    PHASE_END(1, if (more) STAGE_B(1, 1, t0 + 3));
  }

#undef STAGE_A
#undef STAGE_B
#undef LDA2
#undef LDB8
#undef MMA_PAIR
#undef PHASE
#undef PHASE_END

  // epilogue
  const int lc = l & 15;
  const int lr = (l >> 4) * 4;
#pragma unroll
  for (int n = 0; n < 4; ++n) {
    const int col = bn * 256 + wc * 64 + n * 16 + lc;
    const float bv = bias[col];
#pragma unroll
    for (int m = 0; m < 8; ++m) {
      const int row = bm * 256 + wr * 128 + m * 16 + lr;
#pragma unroll
      for (int r2 = 0; r2 < 4; ++r2) {
        float v = acc[m][n][r2] + bv;
        const size_t off = (size_t)(row + r2) * N + col;
        if constexpr (EPI == 1) v = v / (1.f + __expf(-v));
        if constexpr (EPI == 2) {
          ((float*)C)[off] = res[off] + v;
        } else {
          ((bf16*)C)[off] = f2bf(v);
        }
      }
    }
  }
  (void)M;
}

// ---------------- per-head k/th matmuls + gate math -> a,b (bf16, (n,t,D) layout) ------
__global__ __launch_bounds__(256)
void heads_kernel(const bf16* __restrict__ piB,
                  const float* __restrict__ wz, const float* __restrict__ bz,
                  const float* __restrict__ wh, const float* __restrict__ bh,
                  bf16* __restrict__ aB, bf16* __restrict__ bB) {
  __shared__ float wzs[4096], whs[4096], pis[4096];
  const int h = blockIdx.y;
  const int t0 = blockIdx.x * 64;  // global row (n*L + t)
  const int tid = threadIdx.x;
#pragma unroll
  for (int i = tid; i < 4096; i += 256) {
    wzs[i] = wz[i];
    whs[i] = wh[i];
    pis[i] = bf2f(piB[(size_t)(t0 + (i >> 6)) * 1024 + h * 64 + (i & 63)]);
  }
  __syncthreads();
  const int hd = tid & 63;
  const int tb = (tid >> 6) * 16;
  float accK[16], accT[16];
  const float bzv = bz[hd], bhv = bh[hd];
#pragma unroll
  for (int i = 0; i < 16; ++i) { accK[i] = bzv; accT[i] = bhv; }
  for (int j = 0; j < 64; ++j) {
    const float wzv = wzs[j * 64 + hd];
    const float whv = whs[j * 64 + hd];
#pragma unroll
    for (int i = 0; i < 16; ++i) {
      const float p = pis[(tb + i) * 64 + j];
      accK[i] = fmaf(p, wzv, accK[i]);
      accT[i] = fmaf(p, whv, accT[i]);
    }
  }
#pragma unroll
  for (int i = 0; i < 16; ++i) {
    const float k = accK[i], th = accT[i];
    const float sig = 1.f / (1.f + __expf(-k));      // sigmoid(k)
    const float a = 1.f - sig;                        // exp(-softplus(k))
    const float gg = th >= 0.f ? th + 0.5f : 1.f / (1.f + __expf(-th));  // g(th)
    const float bb = sig * gg;                        // exp(log_z + log_th)
    const size_t idx = (size_t)(t0 + tb + i) * 1024 + h * 64 + hd;
    aB[idx] = f2bf(a);
    bB[idx] = f2bf(bb);
  }
}

// ---------------- chunked scan: h_t = a_t*h_{t-1} + b_t ----------------
__global__ __launch_bounds__(256)
void scan_phase1(const bf16* __restrict__ aB, const bf16* __restrict__ bB,
                 float* __restrict__ cA, float* __restrict__ cB) {
  const int idx = blockIdx.x * 256 + threadIdx.x;  // 262144
  const int c = idx & 1023;
  const int chunk = (idx >> 10) & 63;
  const int n = idx >> 16;
  size_t base = ((size_t)(n * 4096 + chunk * 64)) * 1024 + c;
  float A = 1.f, B = 0.f;
#pragma unroll 8
  for (int s = 0; s < 64; ++s) {
    const float a = bf2f(aB[base]);
    const float b = bf2f(bB[base]);
    A *= a;
    B = fmaf(a, B, b);
    base += 1024;
  }
  const size_t o = ((size_t)(n * 64 + chunk)) * 1024 + c;
  cA[o] = A;
  cB[o] = B;
}

__global__ __launch_bounds__(256)
void scan_phase2(const float* __restrict__ h0,
                 const float* __restrict__ cA, const float* __restrict__ cB,
                 float* __restrict__ hst) {
  const int idx = blockIdx.x * 256 + threadIdx.x;  // 4096
  const int c = idx & 1023;
  const int n = idx >> 10;
  float hv = h0[(size_t)n * 1024 + c];
  hv = hv >= 0.f ? hv + 0.5f : 1.f / (1.f + __expf(-hv));  // g(h0)
  for (int ch = 0; ch < 64; ++ch) {
    const size_t o = ((size_t)(n * 64 + ch)) * 1024 + c;
    hst[o] = hv;
    hv = fmaf(cA[o], hv, cB[o]);
  }
}

__global__ __launch_bounds__(256)
void scan_phase3(const bf16* __restrict__ aB, const bf16* __restrict__ bB,
                 const float* __restrict__ hst,
                 float* __restrict__ rnn, bf16* __restrict__ rnnB) {
  const int idx = blockIdx.x * 256 + threadIdx.x;  // 262144
  const int c = idx & 1023;
  const int chunk = (idx >> 10) & 63;
  const int n = idx >> 16;
  float hv = hst[((size_t)(n * 64 + chunk)) * 1024 + c];
  size_t base = ((size_t)(n * 4096 + chunk * 64)) * 1024 + c;
#pragma unroll 4
  for (int s = 0; s < 64; ++s) {
    const float a = bf2f(aB[base]);
    const float b = bf2f(bB[base]);
    hv = fmaf(a, hv, b);
    rnn[base] = hv;       // fp32 rnn_states output (n,t,D)
    rnnB[base] = f2bf(hv);
    base += 1024;
  }
}

// ---------------- host ----------------
extern "C" void kernel_launch(void* const* d_in, const int* in_sizes, int n_in,
                              void* d_out, int out_size, void* d_ws, size_t ws_size,
                              hipStream_t stream) {
  const float* x    = (const float*)d_in[0];
  const float* h0   = (const float*)d_in[1];
  const float* w_in = (const float*)d_in[2];
  const float* b_in = (const float*)d_in[3];
  const float* wz   = (const float*)d_in[4];
  const float* bz   = (const float*)d_in[5];
  const float* wh   = (const float*)d_in[6];
  const float* bh   = (const float*)d_in[7];
  const float* w_out= (const float*)d_in[8];
  const float* b_out= (const float*)d_in[9];
  const float* ln1g = (const float*)d_in[10];
  const float* ln1b = (const float*)d_in[11];
  const float* ln2g = (const float*)d_in[12];
  const float* ln2b = (const float*)d_in[13];
  const float* mw1  = (const float*)d_in[14];
  const float* mb1  = (const float*)d_in[15];
  const float* mw2  = (const float*)d_in[16];
  const float* mb2  = (const float*)d_in[17];
  const float* mw3  = (const float*)d_in[18];
  const float* mb3  = (const float*)d_in[19];
  (void)in_sizes; (void)n_in; (void)out_size;

  float* out0 = (float*)d_out;                       // holds xr, then x+y (in place)
  float* out1 = (float*)d_out + (size_t)16384 * 1024;  // rnn_states

  char* ws = (char*)d_ws;
  size_t o = 0;
  auto take = [&](size_t bytes) { char* p = ws + o; o += (bytes + 255) & ~(size_t)255; return p; };
  bf16* w_inT = (bf16*)take((size_t)1024 * 1024 * 2);
  bf16* w_outT= (bf16*)take((size_t)1024 * 1024 * 2);
  bf16* mw1T  = (bf16*)take((size_t)4096 * 1024 * 2);
  bf16* mw2T  = (bf16*)take((size_t)4096 * 4096 * 2);
  bf16* mw3T  = (bf16*)take((size_t)4096 * 1024 * 2);
  bf16* lnxB  = (bf16*)take((size_t)16384 * 1024 * 2);  // reused: rnnB, ln2B
  bf16* piB   = (bf16*)take((size_t)16384 * 1024 * 2);
  bf16* aB    = (bf16*)take((size_t)16384 * 1024 * 2);  // reused: t1
  bf16* bB    = (bf16*)take((size_t)16384 * 1024 * 2);  // reused: t2
  float* cA   = (float*)take((size_t)4 * 64 * 1024 * 4);
  float* cB   = (float*)take((size_t)4 * 64 * 1024 * 4);
  float* hst  = (float*)take((size_t)4 * 64 * 1024 * 4);
  if (o > ws_size) return;  // workspace too small -> fail loudly via wrong output

  // weights -> bf16, transposed (N,K)
  wconv_kernel<<<dim3(32, 32), 256, 0, stream>>>(w_in, w_inT, 1024, 1024);
  wconv_kernel<<<dim3(32, 32), 256, 0, stream>>>(w_out, w_outT, 1024, 1024);
  wconv_kernel<<<dim3(32, 128), 256, 0, stream>>>(mw1, mw1T, 1024, 4096);
  wconv_kernel<<<dim3(128, 128), 256, 0, stream>>>(mw2, mw2T, 4096, 4096);
  wconv_kernel<<<dim3(128, 32), 256, 0, stream>>>(mw3, mw3T, 4096, 1024);

  // LN1 -> GEMM1 (pi)   (16384/256 x 1024/256 = 256 blocks)
  ln_kernel<<<16384, 256, 0, stream>>>(x, ln1g, ln1b, lnxB);
  gemm256<0><<<256, 512, 0, stream>>>(lnxB, w_inT, b_in, nullptr, piB, 16384, 1024, 1024);

  // per-head gates -> a,b ; chunked scan -> rnn_states (+bf16 copy)
  heads_kernel<<<dim3(256, 16), 256, 0, stream>>>(piB, wz, bz, wh, bh, aB, bB);
  scan_phase1<<<1024, 256, 0, stream>>>(aB, bB, cA, cB);
  scan_phase2<<<16, 256, 0, stream>>>(h0, cA, cB, hst);
  scan_phase3<<<1024, 256, 0, stream>>>(aB, bB, hst, out1, lnxB /*rnnB*/);

  // xr = x + rnn @ w_out + b_out   (written to out0)
  gemm256<2><<<256, 512, 0, stream>>>(lnxB, w_outT, b_out, x, out0, 16384, 1024, 1024);

  // LN2 -> MLP (M-chunked x4), final GEMM adds xr in place in out0
  ln_kernel<<<16384, 256, 0, stream>>>(out0, ln2g, ln2b, lnxB /*ln2B*/);
  bf16* t1 = aB;
  bf16* t2 = bB;
  for (int mc = 0; mc < 4; ++mc) {
    const bf16* a3 = lnxB + (size_t)mc * 4096 * 1024;
    gemm256<1><<<256, 512, 0, stream>>>(a3, mw1T, mb1, nullptr, t1, 4096, 4096, 1024);
    gemm256<1><<<256, 512, 0, stream>>>(t1, mw2T, mb2, nullptr, t2, 4096, 4096, 4096);
    float* oc = out0 + (size_t)mc * 4096 * 1024;
    gemm128<2><<<256, 256, 0, stream>>>(t2, mw3T, mb3, oc, oc, 4096, 1024, 4096);
  }
}